// Round 1
// baseline (1437.759 us; speedup 1.0000x reference)
//
#include <hip/hip_runtime.h>

typedef unsigned short u16;
typedef unsigned int   u32;
typedef __attribute__((ext_vector_type(4))) float f32x4;
typedef __attribute__((ext_vector_type(8))) __bf16 bf16x8;
typedef __attribute__((ext_vector_type(8))) unsigned short u16x8;

#define DEV __device__ __forceinline__

DEV u16 f2bf(float f){
  u32 u = __builtin_bit_cast(u32, f);
  u32 r = (u + 0x7fffu + ((u >> 16) & 1u)) >> 16;
  return (u16)r;
}

DEV f32x4 mfma16(bf16x8 a, bf16x8 b, f32x4 c){
  return __builtin_amdgcn_mfma_f32_16x16x32_bf16(a, b, c, 0, 0, 0);
}

DEV void gload16(const void* g, void* l){
  __builtin_amdgcn_global_load_lds((const __attribute__((address_space(1))) u32*)g,
                                   (__attribute__((address_space(3))) u32*)l, 16, 0, 0);
}

// ---------------- weight transpose + cast: src [R][C] f32 -> dst [C][R] bf16 ----------------
__global__ __launch_bounds__(256) void transpose_cast(const float* __restrict__ src,
                                                      u16* __restrict__ dst, int R, int C){
  __shared__ float tile[32][33];
  int r  = threadIdx.x >> 3;
  int c4 = (threadIdx.x & 7) * 4;
  int r0 = blockIdx.x * 32, c0 = blockIdx.y * 32;
  float4 v = *(const float4*)&src[(size_t)(r0 + r) * C + c0 + c4];
  tile[r][c4+0] = v.x; tile[r][c4+1] = v.y; tile[r][c4+2] = v.z; tile[r][c4+3] = v.w;
  __syncthreads();
  ushort4 o;
  o.x = f2bf(tile[c4+0][r]);
  o.y = f2bf(tile[c4+1][r]);
  o.z = f2bf(tile[c4+2][r]);
  o.w = f2bf(tile[c4+3][r]);
  *(ushort4*)&dst[(size_t)(c0 + r) * R + r0 + c4] = o;
}

// ---------------- inv rms per row (D=1024) ----------------
__global__ __launch_bounds__(256) void rms_inv_k(const float* __restrict__ x, float* __restrict__ inv){
  int row  = blockIdx.x * 4 + (threadIdx.x >> 6);
  int lane = threadIdx.x & 63;
  const float* p = x + (size_t)row * 1024;
  float ss = 0.f;
  #pragma unroll
  for (int j = 0; j < 4; ++j){
    float4 v = *(const float4*)&p[lane*4 + j*256];
    ss += v.x*v.x + v.y*v.y + v.z*v.z + v.w*v.w;
  }
  #pragma unroll
  for (int o = 1; o < 64; o <<= 1) ss += __shfl_xor(ss, o);
  if (lane == 0) inv[row] = 1.f / sqrtf(ss * (1.f/1024.f) + 1e-6f);
}

// ---------------- SSM chunked scan ----------------
// phase A: per (b,chunk,d) local scan with zero init -> F
__global__ __launch_bounds__(1024) void ssm_a_k(const float* __restrict__ hid, const float* __restrict__ invr,
    const float* __restrict__ nw, const float* __restrict__ av, float* __restrict__ Fc){
  int c = blockIdx.x & 63, b = blockIdx.x >> 6;
  int d = threadIdx.x;
  float w   = nw[d];
  float dec = 1.f/(1.f + expf(-av[d]));
  float od  = 1.f - dec;
  const float* hp = hid + ((size_t)b*4096 + c*64)*1024 + d;
  const float* ip = invr + b*4096 + c*64;
  float hs = 0.f;
  for (int i = 0; i < 64; ++i)
    hs = dec*hs + od*(hp[(size_t)i*1024] * ip[i] * w);
  Fc[((size_t)b*64 + c)*1024 + d] = hs;
}
// phase B: combine chunk carries sequentially (64 steps)
__global__ __launch_bounds__(1024) void ssm_b_k(const float* __restrict__ Fc, float* __restrict__ Init,
                                                const float* __restrict__ av){
  int b = blockIdx.x, d = threadIdx.x;
  float dec = 1.f/(1.f + expf(-av[d]));
  float dl  = powf(dec, 64.f);
  float cur = 0.f;
  for (int c = 0; c < 64; ++c){
    size_t o = ((size_t)b*64 + c)*1024 + d;
    Init[o] = cur;
    cur = dl*cur + Fc[o];
  }
}
// phase C: re-scan with correct init, write h = hidden + y*gain
__global__ __launch_bounds__(1024) void ssm_c_k(const float* __restrict__ hid, const float* __restrict__ invr,
    const float* __restrict__ nw, const float* __restrict__ av, const float* __restrict__ gn,
    const float* __restrict__ Init, float* __restrict__ hout){
  int c = blockIdx.x & 63, b = blockIdx.x >> 6;
  int d = threadIdx.x;
  float w   = nw[d];
  float g   = gn[d];
  float dec = 1.f/(1.f + expf(-av[d]));
  float od  = 1.f - dec;
  size_t rowoff = ((size_t)b*4096 + c*64)*1024 + d;
  const float* hp = hid + rowoff;
  float* op = hout + rowoff;
  const float* ip = invr + b*4096 + c*64;
  float hs = Init[((size_t)b*64 + c)*1024 + d];
  for (int i = 0; i < 64; ++i){
    float hv = hp[(size_t)i*1024];
    hs = dec*hs + od*(hv * ip[i] * w);
    op[(size_t)i*1024] = hv + hs*g;
  }
}

// ---------------- router scores ----------------
__global__ __launch_bounds__(256) void score_k(const float* __restrict__ h, const float* __restrict__ rw,
                                               float* __restrict__ sc){
  int row  = blockIdx.x * 4 + (threadIdx.x >> 6);
  int lane = threadIdx.x & 63;
  const float* p = h + (size_t)row * 1024;
  float s = 0.f;
  #pragma unroll
  for (int j = 0; j < 4; ++j){
    float4 v = *(const float4*)&p[lane*4 + j*256];
    float4 w = *(const float4*)&rw[lane*4 + j*256];
    s += v.x*w.x + v.y*w.y + v.z*w.z + v.w*w.w;
  }
  #pragma unroll
  for (int o = 1; o < 64; o <<= 1) s += __shfl_xor(s, o);
  if (lane == 0) sc[row] = s;
}

__global__ __launch_bounds__(256) void aux_k(const float* __restrict__ sc, float* __restrict__ out){
  __shared__ float red[256];
  int tid = threadIdx.x;
  float s = 0.f;
  for (int i = tid; i < 16384; i += 256) s += 1.f/(1.f + expf(-sc[i]));
  red[tid] = s; __syncthreads();
  for (int o = 128; o > 0; o >>= 1){ if (tid < o) red[tid] += red[tid+o]; __syncthreads(); }
  if (tid == 0) out[0] = red[0] * (1.f/16384.f);
}

// ---------------- top-k via bitonic sort (per batch) ----------------
__global__ __launch_bounds__(1024) void topk_k(const float* __restrict__ sc, int* __restrict__ idx,
                                               float* __restrict__ wsel){
  __shared__ float sv[4096];
  __shared__ int   si[4096];
  int b = blockIdx.x, tid = threadIdx.x;
  for (int i = tid; i < 4096; i += 1024){ sv[i] = sc[b*4096 + i]; si[i] = i; }
  __syncthreads();
  // sort all 4096 by (value desc, index asc) -- matches jax top_k tie-break
  for (int k = 2; k <= 4096; k <<= 1)
    for (int j = k >> 1; j > 0; j >>= 1){
      for (int i = tid; i < 4096; i += 1024){
        int p = i ^ j;
        if (p > i){
          float vi = sv[i], vp = sv[p];
          int ii = si[i], ip = si[p];
          bool before = (vi > vp) || (vi == vp && ii < ip);
          bool desc = ((i & k) == 0);
          if (desc ? !before : before){ sv[i]=vp; sv[p]=vi; si[i]=ip; si[p]=ii; }
        }
      }
      __syncthreads();
    }
  // sort top-1024 indices ascending (keep causal order)
  for (int k = 2; k <= 1024; k <<= 1)
    for (int j = k >> 1; j > 0; j >>= 1){
      int i = tid, p = i ^ j;
      if (p > i){
        int a = si[i], c = si[p];
        bool asc = ((i & k) == 0);
        if (asc ? (a > c) : (a < c)){ si[i] = c; si[p] = a; }
      }
      __syncthreads();
    }
  int t = si[tid];
  idx[b*1024 + tid]  = t;
  wsel[b*1024 + tid] = 1.f/(1.f + expf(-sc[b*4096 + t]));
}

// ---------------- rmsnorm row -> bf16 (optional gather) ----------------
__global__ __launch_bounds__(256) void rownorm_bf16_k(const float* __restrict__ src, const float* __restrict__ w,
    u16* __restrict__ dst, const int* __restrict__ gidx, int base){
  int row  = blockIdx.x * 4 + (threadIdx.x >> 6);
  int lane = threadIdx.x & 63;
  size_t srow;
  if (gidx){ int b = row >> 10; srow = (size_t)b*4096 + gidx[row]; }
  else srow = (size_t)(base + row);
  const float* p = src + srow*1024;
  float4 v[4]; float ss = 0.f;
  #pragma unroll
  for (int j = 0; j < 4; ++j){
    v[j] = *(const float4*)&p[lane*4 + j*256];
    ss += v[j].x*v[j].x + v[j].y*v[j].y + v[j].z*v[j].z + v[j].w*v[j].w;
  }
  #pragma unroll
  for (int o = 1; o < 64; o <<= 1) ss += __shfl_xor(ss, o);
  float inv = 1.f / sqrtf(ss * (1.f/1024.f) + 1e-6f);
  #pragma unroll
  for (int j = 0; j < 4; ++j){
    float4 wv = *(const float4*)&w[lane*4 + j*256];
    ushort4 o4;
    o4.x = f2bf(v[j].x*inv*wv.x);
    o4.y = f2bf(v[j].y*inv*wv.y);
    o4.z = f2bf(v[j].z*inv*wv.z);
    o4.w = f2bf(v[j].w*inv*wv.w);
    *(ushort4*)&dst[(size_t)row*1024 + lane*4 + j*256] = o4;
  }
}

// ---------------- GEMM: A[M,K] bf16 x BT[N,K] bf16, 128x128 tile, 4 waves ----------------
// EPI: 0 = store bf16, 1 = silu->bf16, 2 = += fp32, 3 = scatter-add (wo)
template<int EPI>
__global__ __launch_bounds__(256) void gemm_bt(const u16* __restrict__ A, const u16* __restrict__ BT,
    u16* __restrict__ Cb, float* __restrict__ Cf, int M, int N, int K,
    const int* __restrict__ gidx, const float* __restrict__ wsel){
  __shared__ u16 As[128*32];
  __shared__ u16 Bs[128*32];
  int tid  = threadIdx.x;
  int wave = tid >> 6, lane = tid & 63;
  int lr = lane & 15, lg = lane >> 4;
  int bm = blockIdx.x, bn = blockIdx.y;
  int wr = (wave >> 1)*64, wc = (wave & 1)*64;
  f32x4 zero4 = {0.f,0.f,0.f,0.f};
  f32x4 acc[4][4];
  #pragma unroll
  for (int mi = 0; mi < 4; ++mi)
    #pragma unroll
    for (int ni = 0; ni < 4; ++ni) acc[mi][ni] = zero4;

  int blin = wave*1024 + lane*16;            // byte slot in 8KB tile (half per call)
  int row0 = blin >> 6;                      // 64B per row (32 bf16)
  int colb = blin & 63;
  const char* Abase = (const char*)(A + (size_t)(bm*128)*K);
  const char* Bbase = (const char*)(BT + (size_t)(bn*128)*K);
  char* AsB = (char*)As; char* BsB = (char*)Bs;

  for (int k0 = 0; k0 < K; k0 += 32){
    __syncthreads();
    gload16(Abase + (size_t)row0*K*2      + k0*2 + colb, AsB + wave*1024);
    gload16(Abase + (size_t)(row0+64)*K*2 + k0*2 + colb, AsB + 4096 + wave*1024);
    gload16(Bbase + (size_t)row0*K*2      + k0*2 + colb, BsB + wave*1024);
    gload16(Bbase + (size_t)(row0+64)*K*2 + k0*2 + colb, BsB + 4096 + wave*1024);
    __syncthreads();
    bf16x8 af[4], bfr[4];
    #pragma unroll
    for (int mi = 0; mi < 4; ++mi) af[mi]  = *(const bf16x8*)&As[(wr + mi*16 + lr)*32 + lg*8];
    #pragma unroll
    for (int ni = 0; ni < 4; ++ni) bfr[ni] = *(const bf16x8*)&Bs[(wc + ni*16 + lr)*32 + lg*8];
    #pragma unroll
    for (int mi = 0; mi < 4; ++mi)
      #pragma unroll
      for (int ni = 0; ni < 4; ++ni)
        acc[mi][ni] = mfma16(af[mi], bfr[ni], acc[mi][ni]);
  }

  #pragma unroll
  for (int mi = 0; mi < 4; ++mi){
    int rb = bm*128 + wr + mi*16 + lg*4;
    #pragma unroll
    for (int ni = 0; ni < 4; ++ni){
      int col = bn*128 + wc + ni*16 + lr;
      f32x4 v = acc[mi][ni];
      if constexpr (EPI == 0){
        #pragma unroll
        for (int t = 0; t < 4; ++t) Cb[(size_t)(rb+t)*N + col] = f2bf(v[t]);
      } else if constexpr (EPI == 1){
        #pragma unroll
        for (int t = 0; t < 4; ++t){ float x = v[t]; Cb[(size_t)(rb+t)*N + col] = f2bf(x / (1.f + expf(-x))); }
      } else if constexpr (EPI == 2){
        #pragma unroll
        for (int t = 0; t < 4; ++t) Cf[(size_t)(rb+t)*N + col] += v[t];
      } else {
        #pragma unroll
        for (int t = 0; t < 4; ++t){
          int r = rb + t;
          int bb = r >> 10;
          float* hr = Cf + ((size_t)bb*4096 + gidx[r])*1024;
          hr[col] += v[t] * wsel[r];
        }
      }
    }
  }
}

// ---------------- flash attention: block = (b, head, q-tile of 64), 4 waves x 16 q rows ----------------
__global__ __launch_bounds__(256) void attn_k(const u16* __restrict__ qkv, u16* __restrict__ obuf){
  __shared__ u16 Ks[64*64];     // [key][dh]
  __shared__ u16 Vt[64*64];     // [dh][key]
  __shared__ u16 Pl[4*16*64];   // per-wave P [q][key]
  int blk = blockIdx.x;
  int qt = blk & 15;
  int hh = (blk >> 4) & 15;
  int b  = blk >> 8;
  int tid = threadIdx.x;
  int wave = tid >> 6, lane = tid & 63;
  int lr = lane & 15, lg = lane >> 4;

  const u16* qrow = qkv + (size_t)(b*1024 + qt*64 + wave*16 + lr)*3072 + hh*64;
  bf16x8 qf0 = *(const bf16x8*)(qrow + lg*8);
  bf16x8 qf1 = *(const bf16x8*)(qrow + 32 + lg*8);

  f32x4 zero4 = {0.f,0.f,0.f,0.f};
  f32x4 oacc[4];
  #pragma unroll
  for (int d = 0; d < 4; ++d) oacc[d] = zero4;
  float m[4], s[4];
  #pragma unroll
  for (int t = 0; t < 4; ++t){ m[t] = -INFINITY; s[t] = 0.f; }

  for (int kt = 0; kt <= qt; ++kt){
    int k0 = kt*64;
    __syncthreads();
    #pragma unroll
    for (int it = 0; it < 2; ++it){
      int slot = tid + it*256;
      int key = slot >> 3; int ce = (slot & 7)*8;
      const u16* gk = qkv + (size_t)(b*1024 + k0 + key)*3072 + 1024 + hh*64 + ce;
      u16x8 kv = *(const u16x8*)gk;
      *(u16x8*)&Ks[key*64 + ce] = kv;
      u16x8 vv = *(const u16x8*)(gk + 1024);
      #pragma unroll
      for (int j = 0; j < 8; ++j) Vt[(ce+j)*64 + key] = vv[j];
    }
    __syncthreads();

    float sv[4][4];
    #pragma unroll
    for (int kb = 0; kb < 4; ++kb){
      f32x4 sa = zero4;
      bf16x8 k0f = *(const bf16x8*)&Ks[(kb*16 + lr)*64 + lg*8];
      bf16x8 k1f = *(const bf16x8*)&Ks[(kb*16 + lr)*64 + 32 + lg*8];
      sa = mfma16(qf0, k0f, sa);
      sa = mfma16(qf1, k1f, sa);
      #pragma unroll
      for (int t = 0; t < 4; ++t) sv[kb][t] = sa[t]*0.125f;
    }
    if (kt == qt){
      #pragma unroll
      for (int kb = 0; kb < 4; ++kb){
        int keyg = kb*16 + lr;
        #pragma unroll
        for (int t = 0; t < 4; ++t){
          int qg = wave*16 + lg*4 + t;
          if (keyg > qg) sv[kb][t] = -1e30f;
        }
      }
    }
    float mn[4], scale[4];
    #pragma unroll
    for (int t = 0; t < 4; ++t){
      float tm = fmaxf(fmaxf(sv[0][t], sv[1][t]), fmaxf(sv[2][t], sv[3][t]));
      #pragma unroll
      for (int o = 1; o < 16; o <<= 1) tm = fmaxf(tm, __shfl_xor(tm, o));
      mn[t] = fmaxf(m[t], tm);
      scale[t] = expf(m[t] - mn[t]);
      m[t] = mn[t];
    }
    float ps[4] = {0.f,0.f,0.f,0.f};
    #pragma unroll
    for (int kb = 0; kb < 4; ++kb)
      #pragma unroll
      for (int t = 0; t < 4; ++t){
        float p = expf(sv[kb][t] - mn[t]);
        ps[t] += p;
        Pl[wave*1024 + (lg*4 + t)*64 + kb*16 + lr] = f2bf(p);
      }
    #pragma unroll
    for (int t = 0; t < 4; ++t){
      #pragma unroll
      for (int o = 1; o < 16; o <<= 1) ps[t] += __shfl_xor(ps[t], o);
      s[t] = s[t]*scale[t] + ps[t];
    }
    #pragma unroll
    for (int d = 0; d < 4; ++d){
      f32x4 v = oacc[d];
      #pragma unroll
      for (int t = 0; t < 4; ++t) v[t] *= scale[t];
      oacc[d] = v;
    }
    __syncthreads();
    bf16x8 pa0 = *(const bf16x8*)&Pl[wave*1024 + lr*64 + lg*8];
    bf16x8 pa1 = *(const bf16x8*)&Pl[wave*1024 + lr*64 + 32 + lg*8];
    #pragma unroll
    for (int d = 0; d < 4; ++d){
      bf16x8 v0 = *(const bf16x8*)&Vt[(d*16 + lr)*64 + lg*8];
      bf16x8 v1 = *(const bf16x8*)&Vt[(d*16 + lr)*64 + 32 + lg*8];
      oacc[d] = mfma16(pa0, v0, oacc[d]);
      oacc[d] = mfma16(pa1, v1, oacc[d]);
    }
  }
  #pragma unroll
  for (int d = 0; d < 4; ++d)
    #pragma unroll
    for (int t = 0; t < 4; ++t){
      int qrel = qt*64 + wave*16 + lg*4 + t;
      float val = oacc[d][t] / s[t];
      obuf[(size_t)(b*1024 + qrel)*1024 + hh*64 + d*16 + lr] = f2bf(val);
    }
}

// ---------------- launch ----------------
extern "C" void kernel_launch(void* const* d_in, const int* in_sizes, int n_in,
                              void* d_out, int out_size, void* d_ws, size_t ws_size,
                              hipStream_t stream) {
  const float* hid    = (const float*)d_in[0];
  const float* nssm   = (const float*)d_in[1];
  const float* ssma   = (const float*)d_in[2];
  const float* ssmg   = (const float*)d_in[3];
  const float* routw  = (const float*)d_in[4];
  const float* nattn  = (const float*)d_in[5];
  const float* wq     = (const float*)d_in[6];
  const float* wk     = (const float*)d_in[7];
  const float* wv     = (const float*)d_in[8];
  const float* wo     = (const float*)d_in[9];
  const float* nffn   = (const float*)d_in[10];
  const float* w1     = (const float*)d_in[11];
  const float* w2     = (const float*)d_in[12];

  float* hbuf = (float*)d_out;                 // h lives in d_out [4,4096,1024]
  char* wsb = (char*)d_ws;
  u16*   wqkvT  = (u16*)(wsb + 0);             // [3072][1024] bf16
  u16*   woT    = (u16*)(wsb + 6291456);       // [1024][1024]
  u16*   w1T    = (u16*)(wsb + 8388608);       // [4096][1024]
  u16*   w2T    = (u16*)(wsb + 16777216);      // [1024][4096]
  float* invr   = (float*)(wsb + 25165824);    // [B*S]
  float* scores = (float*)(wsb + 25231360);    // [B*S]
  float* Fc     = (float*)(wsb + 25296896);    // [B,64,1024]
  float* Init   = (float*)(wsb + 26345472);    // [B,64,1024]
  int*   idxb   = (int*)(wsb + 27394048);      // [B,1024]
  float* wselb  = (float*)(wsb + 27410432);    // [B,1024]
  u16*   xn     = (u16*)(wsb + 27426816);      // [4096][1024] bf16
  u16*   qkv    = (u16*)(wsb + 35815424);      // [4096][3072] bf16
  u16*   obuf   = (u16*)(wsb + 60981248);      // [4096][1024] bf16
  u16*   xf     = qkv;                         // overlay: FFN phase after attn done with qkv
  u16*   act    = (u16*)((char*)qkv + 4194304);

  // weights -> bf16 transposed
  transpose_cast<<<dim3(32,32),  256, 0, stream>>>(wq, wqkvT,              1024, 1024);
  transpose_cast<<<dim3(32,32),  256, 0, stream>>>(wk, wqkvT + 1048576,    1024, 1024);
  transpose_cast<<<dim3(32,32),  256, 0, stream>>>(wv, wqkvT + 2097152,    1024, 1024);
  transpose_cast<<<dim3(32,32),  256, 0, stream>>>(wo, woT,                1024, 1024);
  transpose_cast<<<dim3(32,128), 256, 0, stream>>>(w1, w1T,                1024, 4096);
  transpose_cast<<<dim3(128,32), 256, 0, stream>>>(w2, w2T,                4096, 1024);

  // SSM
  rms_inv_k<<<4096, 256, 0, stream>>>(hid, invr);
  ssm_a_k<<<256, 1024, 0, stream>>>(hid, invr, nssm, ssma, Fc);
  ssm_b_k<<<4,   1024, 0, stream>>>(Fc, Init, ssma);
  ssm_c_k<<<256, 1024, 0, stream>>>(hid, invr, nssm, ssma, ssmg, Init, hbuf);

  // router
  score_k<<<4096, 256, 0, stream>>>(hbuf, routw, scores);
  aux_k<<<1, 256, 0, stream>>>(scores, hbuf + 16777216);
  topk_k<<<4, 1024, 0, stream>>>(scores, idxb, wselb);

  // attention path
  rownorm_bf16_k<<<1024, 256, 0, stream>>>(hbuf, nattn, xn, idxb, 0);
  gemm_bt<0><<<dim3(32,24), 256, 0, stream>>>(xn, wqkvT, qkv, nullptr, 4096, 3072, 1024, nullptr, nullptr);
  attn_k<<<1024, 256, 0, stream>>>(qkv, obuf);
  gemm_bt<3><<<dim3(32,8), 256, 0, stream>>>(obuf, woT, nullptr, hbuf, 4096, 1024, 1024, idxb, wselb);

  // FFN in 8 row-chunks of 2048
  for (int ch = 0; ch < 8; ++ch){
    int m0 = ch * 2048;
    rownorm_bf16_k<<<512, 256, 0, stream>>>(hbuf, nffn, xf, nullptr, m0);
    gemm_bt<1><<<dim3(16,32), 256, 0, stream>>>(xf, w1T, act, nullptr, 2048, 4096, 1024, nullptr, nullptr);
    gemm_bt<2><<<dim3(16,8), 256, 0, stream>>>(act, w2T, nullptr, hbuf + (size_t)m0*1024, 2048, 1024, 4096, nullptr, nullptr);
  }
  (void)in_sizes; (void)n_in; (void)out_size; (void)ws_size;
}

// Round 2
// 1036.943 us; speedup vs baseline: 1.3865x; 1.3865x over previous
//
#include <hip/hip_runtime.h>

typedef unsigned short u16;
typedef unsigned int   u32;
typedef __attribute__((ext_vector_type(4))) float f32x4;
typedef __attribute__((ext_vector_type(8))) __bf16 bf16x8;
typedef __attribute__((ext_vector_type(8))) unsigned short u16x8;

#define DEV __device__ __forceinline__

DEV u16 f2bf(float f){
  u32 u = __builtin_bit_cast(u32, f);
  u32 r = (u + 0x7fffu + ((u >> 16) & 1u)) >> 16;
  return (u16)r;
}

DEV f32x4 mfma16(bf16x8 a, bf16x8 b, f32x4 c){
  return __builtin_amdgcn_mfma_f32_16x16x32_bf16(a, b, c, 0, 0, 0);
}

DEV void gload16(const void* g, void* l){
  __builtin_amdgcn_global_load_lds((const __attribute__((address_space(1))) u32*)g,
                                   (__attribute__((address_space(3))) u32*)l, 16, 0, 0);
}

// XOR swizzle for [row][64 bf16] LDS tiles (128B row stride).
// group g = 16B chunk index (0..7). g' = g ^ (row&7) ^ ((row>>3)&7):
// conflict-free for row-strided fragment reads AND stride-8-row scatter writes.
DEV int swz16(int r, int g){ return r*64 + 8*(g ^ (r&7) ^ ((r>>3)&7)); }
DEV int swze (int r, int e){ return r*64 + (e&7) + 8*(((e>>3) ^ (r&7) ^ ((r>>3)&7))); }

// ---------------- weight transpose + cast: src [R][C] f32 -> dst [C][R] bf16 ----------------
__global__ __launch_bounds__(256) void transpose_cast(const float* __restrict__ src,
                                                      u16* __restrict__ dst, int R, int C){
  __shared__ float tile[32][33];
  int r  = threadIdx.x >> 3;
  int c4 = (threadIdx.x & 7) * 4;
  int r0 = blockIdx.x * 32, c0 = blockIdx.y * 32;
  float4 v = *(const float4*)&src[(size_t)(r0 + r) * C + c0 + c4];
  tile[r][c4+0] = v.x; tile[r][c4+1] = v.y; tile[r][c4+2] = v.z; tile[r][c4+3] = v.w;
  __syncthreads();
  ushort4 o;
  o.x = f2bf(tile[c4+0][r]);
  o.y = f2bf(tile[c4+1][r]);
  o.z = f2bf(tile[c4+2][r]);
  o.w = f2bf(tile[c4+3][r]);
  *(ushort4*)&dst[(size_t)(c0 + r) * R + r0 + c4] = o;
}

// ---------------- inv rms per row (D=1024) ----------------
__global__ __launch_bounds__(256) void rms_inv_k(const float* __restrict__ x, float* __restrict__ inv){
  int row  = blockIdx.x * 4 + (threadIdx.x >> 6);
  int lane = threadIdx.x & 63;
  const float* p = x + (size_t)row * 1024;
  float ss = 0.f;
  #pragma unroll
  for (int j = 0; j < 4; ++j){
    float4 v = *(const float4*)&p[lane*4 + j*256];
    ss += v.x*v.x + v.y*v.y + v.z*v.z + v.w*v.w;
  }
  #pragma unroll
  for (int o = 1; o < 64; o <<= 1) ss += __shfl_xor(ss, o);
  if (lane == 0) inv[row] = 1.f / sqrtf(ss * (1.f/1024.f) + 1e-6f);
}

// ---------------- SSM chunked scan ----------------
__global__ __launch_bounds__(1024) void ssm_a_k(const float* __restrict__ hid, const float* __restrict__ invr,
    const float* __restrict__ nw, const float* __restrict__ av, float* __restrict__ Fc){
  int c = blockIdx.x & 63, b = blockIdx.x >> 6;
  int d = threadIdx.x;
  float w   = nw[d];
  float dec = 1.f/(1.f + expf(-av[d]));
  float od  = 1.f - dec;
  const float* hp = hid + ((size_t)b*4096 + c*64)*1024 + d;
  const float* ip = invr + b*4096 + c*64;
  float hs = 0.f;
  for (int i = 0; i < 64; ++i)
    hs = dec*hs + od*(hp[(size_t)i*1024] * ip[i] * w);
  Fc[((size_t)b*64 + c)*1024 + d] = hs;
}
__global__ __launch_bounds__(1024) void ssm_b_k(const float* __restrict__ Fc, float* __restrict__ Init,
                                                const float* __restrict__ av){
  int b = blockIdx.x, d = threadIdx.x;
  float dec = 1.f/(1.f + expf(-av[d]));
  float dl  = powf(dec, 64.f);
  float cur = 0.f;
  for (int c = 0; c < 64; ++c){
    size_t o = ((size_t)b*64 + c)*1024 + d;
    Init[o] = cur;
    cur = dl*cur + Fc[o];
  }
}
__global__ __launch_bounds__(1024) void ssm_c_k(const float* __restrict__ hid, const float* __restrict__ invr,
    const float* __restrict__ nw, const float* __restrict__ av, const float* __restrict__ gn,
    const float* __restrict__ Init, float* __restrict__ hout){
  int c = blockIdx.x & 63, b = blockIdx.x >> 6;
  int d = threadIdx.x;
  float w   = nw[d];
  float g   = gn[d];
  float dec = 1.f/(1.f + expf(-av[d]));
  float od  = 1.f - dec;
  size_t rowoff = ((size_t)b*4096 + c*64)*1024 + d;
  const float* hp = hid + rowoff;
  float* op = hout + rowoff;
  const float* ip = invr + b*4096 + c*64;
  float hs = Init[((size_t)b*64 + c)*1024 + d];
  for (int i = 0; i < 64; ++i){
    float hv = hp[(size_t)i*1024];
    hs = dec*hs + od*(hv * ip[i] * w);
    op[(size_t)i*1024] = hv + hs*g;
  }
}

// ---------------- router scores ----------------
__global__ __launch_bounds__(256) void score_k(const float* __restrict__ h, const float* __restrict__ rw,
                                               float* __restrict__ sc){
  int row  = blockIdx.x * 4 + (threadIdx.x >> 6);
  int lane = threadIdx.x & 63;
  const float* p = h + (size_t)row * 1024;
  float s = 0.f;
  #pragma unroll
  for (int j = 0; j < 4; ++j){
    float4 v = *(const float4*)&p[lane*4 + j*256];
    float4 w = *(const float4*)&rw[lane*4 + j*256];
    s += v.x*w.x + v.y*w.y + v.z*w.z + v.w*w.w;
  }
  #pragma unroll
  for (int o = 1; o < 64; o <<= 1) s += __shfl_xor(s, o);
  if (lane == 0) sc[row] = s;
}

__global__ __launch_bounds__(256) void aux_k(const float* __restrict__ sc, float* __restrict__ out){
  __shared__ float red[256];
  int tid = threadIdx.x;
  float s = 0.f;
  for (int i = tid; i < 16384; i += 256) s += 1.f/(1.f + expf(-sc[i]));
  red[tid] = s; __syncthreads();
  for (int o = 128; o > 0; o >>= 1){ if (tid < o) red[tid] += red[tid+o]; __syncthreads(); }
  if (tid == 0) out[0] = red[0] * (1.f/16384.f);
}

// ---------------- top-k via bitonic sort (per batch) ----------------
__global__ __launch_bounds__(1024) void topk_k(const float* __restrict__ sc, int* __restrict__ idx,
                                               float* __restrict__ wsel){
  __shared__ float sv[4096];
  __shared__ int   si[4096];
  int b = blockIdx.x, tid = threadIdx.x;
  for (int i = tid; i < 4096; i += 1024){ sv[i] = sc[b*4096 + i]; si[i] = i; }
  __syncthreads();
  for (int k = 2; k <= 4096; k <<= 1)
    for (int j = k >> 1; j > 0; j >>= 1){
      for (int i = tid; i < 4096; i += 1024){
        int p = i ^ j;
        if (p > i){
          float vi = sv[i], vp = sv[p];
          int ii = si[i], ip = si[p];
          bool before = (vi > vp) || (vi == vp && ii < ip);
          bool desc = ((i & k) == 0);
          if (desc ? !before : before){ sv[i]=vp; sv[p]=vi; si[i]=ip; si[p]=ii; }
        }
      }
      __syncthreads();
    }
  for (int k = 2; k <= 1024; k <<= 1)
    for (int j = k >> 1; j > 0; j >>= 1){
      int i = tid, p = i ^ j;
      if (p > i){
        int a = si[i], c = si[p];
        bool asc = ((i & k) == 0);
        if (asc ? (a > c) : (a < c)){ si[i] = c; si[p] = a; }
      }
      __syncthreads();
    }
  int t = si[tid];
  idx[b*1024 + tid]  = t;
  wsel[b*1024 + tid] = 1.f/(1.f + expf(-sc[b*4096 + t]));
}

// ---------------- rmsnorm row -> bf16 (optional gather) ----------------
__global__ __launch_bounds__(256) void rownorm_bf16_k(const float* __restrict__ src, const float* __restrict__ w,
    u16* __restrict__ dst, const int* __restrict__ gidx, int base){
  int row  = blockIdx.x * 4 + (threadIdx.x >> 6);
  int lane = threadIdx.x & 63;
  size_t srow;
  if (gidx){ int b = row >> 10; srow = (size_t)b*4096 + gidx[row]; }
  else srow = (size_t)(base + row);
  const float* p = src + srow*1024;
  float4 v[4]; float ss = 0.f;
  #pragma unroll
  for (int j = 0; j < 4; ++j){
    v[j] = *(const float4*)&p[lane*4 + j*256];
    ss += v[j].x*v[j].x + v[j].y*v[j].y + v[j].z*v[j].z + v[j].w*v[j].w;
  }
  #pragma unroll
  for (int o = 1; o < 64; o <<= 1) ss += __shfl_xor(ss, o);
  float inv = 1.f / sqrtf(ss * (1.f/1024.f) + 1e-6f);
  #pragma unroll
  for (int j = 0; j < 4; ++j){
    float4 wv = *(const float4*)&w[lane*4 + j*256];
    ushort4 o4;
    o4.x = f2bf(v[j].x*inv*wv.x);
    o4.y = f2bf(v[j].y*inv*wv.y);
    o4.z = f2bf(v[j].z*inv*wv.z);
    o4.w = f2bf(v[j].w*inv*wv.w);
    *(ushort4*)&dst[(size_t)row*1024 + lane*4 + j*256] = o4;
  }
}

// ---------------- GEMM: A[M,K] bf16 x BT[N,K] bf16, 128x128 tile, 4 waves ----------------
// EPI: 0 = store bf16, 1 = silu->bf16, 2 = += fp32, 3 = scatter-add (wo)
template<int EPI>
__global__ __launch_bounds__(256) void gemm_bt(const u16* __restrict__ A, const u16* __restrict__ BT,
    u16* __restrict__ Cb, float* __restrict__ Cf, int M, int N, int K,
    const int* __restrict__ gidx, const float* __restrict__ wsel){
  __shared__ u16 As[128*32];
  __shared__ u16 Bs[128*32];
  int tid  = threadIdx.x;
  int wave = tid >> 6, lane = tid & 63;
  int lr = lane & 15, lg = lane >> 4;
  int bm = blockIdx.x, bn = blockIdx.y;
  int wr = (wave >> 1)*64, wc = (wave & 1)*64;
  f32x4 zero4 = {0.f,0.f,0.f,0.f};
  f32x4 acc[4][4];
  #pragma unroll
  for (int mi = 0; mi < 4; ++mi)
    #pragma unroll
    for (int ni = 0; ni < 4; ++ni) acc[mi][ni] = zero4;

  int blin = wave*1024 + lane*16;
  int row0 = blin >> 6;
  int colb = blin & 63;
  const char* Abase = (const char*)(A + (size_t)(bm*128)*K);
  const char* Bbase = (const char*)(BT + (size_t)(bn*128)*K);
  char* AsB = (char*)As; char* BsB = (char*)Bs;

  for (int k0 = 0; k0 < K; k0 += 32){
    __syncthreads();
    gload16(Abase + (size_t)row0*K*2      + k0*2 + colb, AsB + wave*1024);
    gload16(Abase + (size_t)(row0+64)*K*2 + k0*2 + colb, AsB + 4096 + wave*1024);
    gload16(Bbase + (size_t)row0*K*2      + k0*2 + colb, BsB + wave*1024);
    gload16(Bbase + (size_t)(row0+64)*K*2 + k0*2 + colb, BsB + 4096 + wave*1024);
    __syncthreads();
    bf16x8 af[4], bfr[4];
    #pragma unroll
    for (int mi = 0; mi < 4; ++mi) af[mi]  = *(const bf16x8*)&As[(wr + mi*16 + lr)*32 + lg*8];
    #pragma unroll
    for (int ni = 0; ni < 4; ++ni) bfr[ni] = *(const bf16x8*)&Bs[(wc + ni*16 + lr)*32 + lg*8];
    #pragma unroll
    for (int mi = 0; mi < 4; ++mi)
      #pragma unroll
      for (int ni = 0; ni < 4; ++ni)
        acc[mi][ni] = mfma16(af[mi], bfr[ni], acc[mi][ni]);
  }

  #pragma unroll
  for (int mi = 0; mi < 4; ++mi){
    int rb = bm*128 + wr + mi*16 + lg*4;
    #pragma unroll
    for (int ni = 0; ni < 4; ++ni){
      int col = bn*128 + wc + ni*16 + lr;
      f32x4 v = acc[mi][ni];
      if constexpr (EPI == 0){
        #pragma unroll
        for (int t = 0; t < 4; ++t) Cb[(size_t)(rb+t)*N + col] = f2bf(v[t]);
      } else if constexpr (EPI == 1){
        #pragma unroll
        for (int t = 0; t < 4; ++t){ float x = v[t]; Cb[(size_t)(rb+t)*N + col] = f2bf(x / (1.f + expf(-x))); }
      } else if constexpr (EPI == 2){
        #pragma unroll
        for (int t = 0; t < 4; ++t) Cf[(size_t)(rb+t)*N + col] += v[t];
      } else {
        #pragma unroll
        for (int t = 0; t < 4; ++t){
          int r = rb + t;
          int bb = r >> 10;
          float* hr = Cf + ((size_t)bb*4096 + gidx[r])*1024;
          hr[col] += v[t] * wsel[r];
        }
      }
    }
  }
}

// ---------------- flash attention: block = (b, head, q-tile of 64), 4 waves x 16 q rows ----------------
// Swizzled LDS (conflict-free) + reg-staged K/V double buffer (T14).
__global__ __launch_bounds__(256) void attn_k(const u16* __restrict__ qkv, u16* __restrict__ obuf){
  __shared__ u16 Ks[64*64];     // [key][dh], swizzled
  __shared__ u16 Vt[64*64];     // [dh][key], swizzled
  __shared__ u16 Pl[4*16*64];   // per-wave P [q][key], swizzled
  int blk = blockIdx.x;
  int qt = blk & 15;
  int hh = (blk >> 4) & 15;
  int b  = blk >> 8;
  int tid = threadIdx.x;
  int wave = tid >> 6, lane = tid & 63;
  int lr = lane & 15, lg = lane >> 4;

  const u16* qrow = qkv + (size_t)(b*1024 + qt*64 + wave*16 + lr)*3072 + hh*64;
  bf16x8 qf0 = *(const bf16x8*)(qrow + lg*8);
  bf16x8 qf1 = *(const bf16x8*)(qrow + 32 + lg*8);

  f32x4 zero4 = {0.f,0.f,0.f,0.f};
  f32x4 oacc[4];
  #pragma unroll
  for (int d = 0; d < 4; ++d) oacc[d] = zero4;
  float m[4], s[4];
  #pragma unroll
  for (int t = 0; t < 4; ++t){ m[t] = -INFINITY; s[t] = 0.f; }

  // staging registers (2 slots/thread covering 512 (key,ce) pairs)
  int key0 = tid >> 3,        ce0 = (tid & 7) * 8;
  int key1 = (tid + 256) >> 3, ce1 = ((tid + 256) & 7) * 8;
  u16x8 kreg0, kreg1, vreg0, vreg1;

  const u16* kvbase = qkv + (size_t)(b*1024)*3072 + 1024 + hh*64;
  {
    const u16* g0 = kvbase + (size_t)key0*3072 + ce0;
    const u16* g1 = kvbase + (size_t)key1*3072 + ce1;
    kreg0 = *(const u16x8*)g0;  vreg0 = *(const u16x8*)(g0 + 1024);
    kreg1 = *(const u16x8*)g1;  vreg1 = *(const u16x8*)(g1 + 1024);
  }

  for (int kt = 0; kt <= qt; ++kt){
    __syncthreads();   // all waves done reading LDS from previous tile
    // commit staged K/V to swizzled LDS
    *(u16x8*)&Ks[swz16(key0, ce0 >> 3)] = kreg0;
    *(u16x8*)&Ks[swz16(key1, ce1 >> 3)] = kreg1;
    #pragma unroll
    for (int j = 0; j < 8; ++j) Vt[swze(ce0 + j, key0)] = vreg0[j];
    #pragma unroll
    for (int j = 0; j < 8; ++j) Vt[swze(ce1 + j, key1)] = vreg1[j];
    __syncthreads();
    // prefetch next tile into regs (overlaps with compute below)
    if (kt < qt){
      const u16* g0 = kvbase + (size_t)((kt+1)*64 + key0)*3072 + ce0;
      const u16* g1 = kvbase + (size_t)((kt+1)*64 + key1)*3072 + ce1;
      kreg0 = *(const u16x8*)g0;  vreg0 = *(const u16x8*)(g0 + 1024);
      kreg1 = *(const u16x8*)g1;  vreg1 = *(const u16x8*)(g1 + 1024);
    }

    float sv[4][4];
    #pragma unroll
    for (int kb = 0; kb < 4; ++kb){
      f32x4 sa = zero4;
      bf16x8 k0f = *(const bf16x8*)&Ks[swz16(kb*16 + lr, lg)];
      bf16x8 k1f = *(const bf16x8*)&Ks[swz16(kb*16 + lr, 4 + lg)];
      sa = mfma16(qf0, k0f, sa);
      sa = mfma16(qf1, k1f, sa);
      #pragma unroll
      for (int t = 0; t < 4; ++t) sv[kb][t] = sa[t]*0.125f;
    }
    if (kt == qt){
      #pragma unroll
      for (int kb = 0; kb < 4; ++kb){
        int keyg = kb*16 + lr;
        #pragma unroll
        for (int t = 0; t < 4; ++t){
          int qg = wave*16 + lg*4 + t;
          if (keyg > qg) sv[kb][t] = -1e30f;
        }
      }
    }
    float mn[4], scale[4];
    #pragma unroll
    for (int t = 0; t < 4; ++t){
      float tm = fmaxf(fmaxf(sv[0][t], sv[1][t]), fmaxf(sv[2][t], sv[3][t]));
      #pragma unroll
      for (int o = 1; o < 16; o <<= 1) tm = fmaxf(tm, __shfl_xor(tm, o));
      mn[t] = fmaxf(m[t], tm);
      scale[t] = expf(m[t] - mn[t]);
      m[t] = mn[t];
    }
    float ps[4] = {0.f,0.f,0.f,0.f};
    #pragma unroll
    for (int kb = 0; kb < 4; ++kb)
      #pragma unroll
      for (int t = 0; t < 4; ++t){
        float p = expf(sv[kb][t] - mn[t]);
        ps[t] += p;
        Pl[wave*1024 + swze(lg*4 + t, kb*16 + lr)] = f2bf(p);
      }
    #pragma unroll
    for (int t = 0; t < 4; ++t){
      #pragma unroll
      for (int o = 1; o < 16; o <<= 1) ps[t] += __shfl_xor(ps[t], o);
      s[t] = s[t]*scale[t] + ps[t];
    }
    #pragma unroll
    for (int d = 0; d < 4; ++d){
      f32x4 v = oacc[d];
      #pragma unroll
      for (int t = 0; t < 4; ++t) v[t] *= scale[t];
      oacc[d] = v;
    }
    // Pl is per-wave private: no barrier needed (lgkmcnt ordering only)
    bf16x8 pa0 = *(const bf16x8*)&Pl[wave*1024 + swz16(lr, lg)];
    bf16x8 pa1 = *(const bf16x8*)&Pl[wave*1024 + swz16(lr, 4 + lg)];
    #pragma unroll
    for (int d = 0; d < 4; ++d){
      bf16x8 v0 = *(const bf16x8*)&Vt[swz16(d*16 + lr, lg)];
      bf16x8 v1 = *(const bf16x8*)&Vt[swz16(d*16 + lr, 4 + lg)];
      oacc[d] = mfma16(pa0, v0, oacc[d]);
      oacc[d] = mfma16(pa1, v1, oacc[d]);
    }
  }
  #pragma unroll
  for (int d = 0; d < 4; ++d)
    #pragma unroll
    for (int t = 0; t < 4; ++t){
      int qrel = qt*64 + wave*16 + lg*4 + t;
      float val = oacc[d][t] / s[t];
      obuf[(size_t)(b*1024 + qrel)*1024 + hh*64 + d*16 + lr] = f2bf(val);
    }
}

// ---------------- launch ----------------
extern "C" void kernel_launch(void* const* d_in, const int* in_sizes, int n_in,
                              void* d_out, int out_size, void* d_ws, size_t ws_size,
                              hipStream_t stream) {
  const float* hid    = (const float*)d_in[0];
  const float* nssm   = (const float*)d_in[1];
  const float* ssma   = (const float*)d_in[2];
  const float* ssmg   = (const float*)d_in[3];
  const float* routw  = (const float*)d_in[4];
  const float* nattn  = (const float*)d_in[5];
  const float* wq     = (const float*)d_in[6];
  const float* wk     = (const float*)d_in[7];
  const float* wv     = (const float*)d_in[8];
  const float* wo     = (const float*)d_in[9];
  const float* nffn   = (const float*)d_in[10];
  const float* w1     = (const float*)d_in[11];
  const float* w2     = (const float*)d_in[12];

  float* hbuf = (float*)d_out;                 // h lives in d_out [4,4096,1024]
  char* wsb = (char*)d_ws;
  u16*   wqkvT  = (u16*)(wsb + 0);             // [3072][1024] bf16
  u16*   woT    = (u16*)(wsb + 6291456);       // [1024][1024]
  u16*   w1T    = (u16*)(wsb + 8388608);       // [4096][1024]
  u16*   w2T    = (u16*)(wsb + 16777216);      // [1024][4096]
  float* invr   = (float*)(wsb + 25165824);    // [B*S]
  float* scores = (float*)(wsb + 25231360);    // [B*S]
  float* Fc     = (float*)(wsb + 25296896);    // [B,64,1024]
  float* Init   = (float*)(wsb + 26345472);    // [B,64,1024]
  int*   idxb   = (int*)(wsb + 27394048);      // [B,1024]
  float* wselb  = (float*)(wsb + 27410432);    // [B,1024]
  u16*   xn     = (u16*)(wsb + 27426816);      // [4096][1024] bf16
  u16*   qkv    = (u16*)(wsb + 35815424);      // [4096][3072] bf16
  u16*   obuf   = (u16*)(wsb + 60981248);      // [4096][1024] bf16
  // FFN phase (after WO gemm): reuse idxb-onward region
  u16*   xf     = (u16*)(wsb + 27394048);      // [4096][1024] bf16 (8 MB)
  u16*   act    = (u16*)(wsb + 35782656);      // [4096][4096] bf16 (32 MB), ends 69,337,088

  // weights -> bf16 transposed
  transpose_cast<<<dim3(32,32),  256, 0, stream>>>(wq, wqkvT,              1024, 1024);
  transpose_cast<<<dim3(32,32),  256, 0, stream>>>(wk, wqkvT + 1048576,    1024, 1024);
  transpose_cast<<<dim3(32,32),  256, 0, stream>>>(wv, wqkvT + 2097152,    1024, 1024);
  transpose_cast<<<dim3(32,32),  256, 0, stream>>>(wo, woT,                1024, 1024);
  transpose_cast<<<dim3(32,128), 256, 0, stream>>>(w1, w1T,                1024, 4096);
  transpose_cast<<<dim3(128,32), 256, 0, stream>>>(w2, w2T,                4096, 1024);

  // SSM
  rms_inv_k<<<4096, 256, 0, stream>>>(hid, invr);
  ssm_a_k<<<256, 1024, 0, stream>>>(hid, invr, nssm, ssma, Fc);
  ssm_b_k<<<4,   1024, 0, stream>>>(Fc, Init, ssma);
  ssm_c_k<<<256, 1024, 0, stream>>>(hid, invr, nssm, ssma, ssmg, Init, hbuf);

  // router
  score_k<<<4096, 256, 0, stream>>>(hbuf, routw, scores);
  aux_k<<<1, 256, 0, stream>>>(scores, hbuf + 16777216);
  topk_k<<<4, 1024, 0, stream>>>(scores, idxb, wselb);

  // attention path
  rownorm_bf16_k<<<1024, 256, 0, stream>>>(hbuf, nattn, xn, idxb, 0);
  gemm_bt<0><<<dim3(32,24), 256, 0, stream>>>(xn, wqkvT, qkv, nullptr, 4096, 3072, 1024, nullptr, nullptr);
  attn_k<<<1024, 256, 0, stream>>>(qkv, obuf);
  gemm_bt<3><<<dim3(32,8), 256, 0, stream>>>(obuf, woT, nullptr, hbuf, 4096, 1024, 1024, idxb, wselb);

  // FFN in 4 row-chunks of 4096
  for (int ch = 0; ch < 4; ++ch){
    int m0 = ch * 4096;
    rownorm_bf16_k<<<1024, 256, 0, stream>>>(hbuf, nffn, xf, nullptr, m0);
    gemm_bt<1><<<dim3(32,32), 256, 0, stream>>>(xf, w1T, act, nullptr, 4096, 4096, 1024, nullptr, nullptr);
    gemm_bt<2><<<dim3(32,8), 256, 0, stream>>>(act, w2T, nullptr, hbuf + (size_t)m0*1024, 4096, 1024, 4096, nullptr, nullptr);
  }
  (void)in_sizes; (void)n_in; (void)out_size; (void)ws_size;
}

// Round 3
// 829.807 us; speedup vs baseline: 1.7326x; 1.2496x over previous
//
#include <hip/hip_runtime.h>

typedef unsigned short u16;
typedef unsigned int   u32;
typedef __attribute__((ext_vector_type(4))) float f32x4;
typedef __attribute__((ext_vector_type(8))) __bf16 bf16x8;
typedef __attribute__((ext_vector_type(8))) unsigned short u16x8;

#define DEV __device__ __forceinline__

DEV u16 f2bf(float f){
  u32 u = __builtin_bit_cast(u32, f);
  u32 r = (u + 0x7fffu + ((u >> 16) & 1u)) >> 16;
  return (u16)r;
}

DEV f32x4 mfma16(bf16x8 a, bf16x8 b, f32x4 c){
  return __builtin_amdgcn_mfma_f32_16x16x32_bf16(a, b, c, 0, 0, 0);
}

DEV void gload16(const void* g, void* l){
  __builtin_amdgcn_global_load_lds((const __attribute__((address_space(1))) u32*)g,
                                   (__attribute__((address_space(3))) u32*)l, 16, 0, 0);
}

// XOR swizzle for [row][64 bf16] LDS tiles (128B row stride), 16B-group granularity.
DEV int swz16(int r, int g){ return r*64 + 8*(g ^ (r&7) ^ ((r>>3)&7)); }
DEV int swze (int r, int e){ return r*64 + (e&7) + 8*(((e>>3) ^ (r&7) ^ ((r>>3)&7))); }

// ---------------- weight transpose + cast: src [R][C] f32 -> dst [C][R] bf16 ----------------
__global__ __launch_bounds__(256) void transpose_cast(const float* __restrict__ src,
                                                      u16* __restrict__ dst, int R, int C){
  __shared__ float tile[32][33];
  int r  = threadIdx.x >> 3;
  int c4 = (threadIdx.x & 7) * 4;
  int r0 = blockIdx.x * 32, c0 = blockIdx.y * 32;
  float4 v = *(const float4*)&src[(size_t)(r0 + r) * C + c0 + c4];
  tile[r][c4+0] = v.x; tile[r][c4+1] = v.y; tile[r][c4+2] = v.z; tile[r][c4+3] = v.w;
  __syncthreads();
  ushort4 o;
  o.x = f2bf(tile[c4+0][r]);
  o.y = f2bf(tile[c4+1][r]);
  o.z = f2bf(tile[c4+2][r]);
  o.w = f2bf(tile[c4+3][r]);
  *(ushort4*)&dst[(size_t)(c0 + r) * R + r0 + c4] = o;
}

// ---------------- inv rms per row (D=1024) ----------------
__global__ __launch_bounds__(256) void rms_inv_k(const float* __restrict__ x, float* __restrict__ inv){
  int row  = blockIdx.x * 4 + (threadIdx.x >> 6);
  int lane = threadIdx.x & 63;
  const float* p = x + (size_t)row * 1024;
  float ss = 0.f;
  #pragma unroll
  for (int j = 0; j < 4; ++j){
    float4 v = *(const float4*)&p[lane*4 + j*256];
    ss += v.x*v.x + v.y*v.y + v.z*v.z + v.w*v.w;
  }
  #pragma unroll
  for (int o = 1; o < 64; o <<= 1) ss += __shfl_xor(ss, o);
  if (lane == 0) inv[row] = 1.f / sqrtf(ss * (1.f/1024.f) + 1e-6f);
}

// ---------------- SSM chunked scan ----------------
__global__ __launch_bounds__(1024) void ssm_a_k(const float* __restrict__ hid, const float* __restrict__ invr,
    const float* __restrict__ nw, const float* __restrict__ av, float* __restrict__ Fc){
  int c = blockIdx.x & 63, b = blockIdx.x >> 6;
  int d = threadIdx.x;
  float w   = nw[d];
  float dec = 1.f/(1.f + expf(-av[d]));
  float od  = 1.f - dec;
  const float* hp = hid + ((size_t)b*4096 + c*64)*1024 + d;
  const float* ip = invr + b*4096 + c*64;
  float hs = 0.f;
  for (int i = 0; i < 64; ++i)
    hs = dec*hs + od*(hp[(size_t)i*1024] * ip[i] * w);
  Fc[((size_t)b*64 + c)*1024 + d] = hs;
}
__global__ __launch_bounds__(1024) void ssm_b_k(const float* __restrict__ Fc, float* __restrict__ Init,
                                                const float* __restrict__ av){
  int b = blockIdx.x, d = threadIdx.x;
  float dec = 1.f/(1.f + expf(-av[d]));
  float dl  = powf(dec, 64.f);
  float cur = 0.f;
  for (int c = 0; c < 64; ++c){
    size_t o = ((size_t)b*64 + c)*1024 + d;
    Init[o] = cur;
    cur = dl*cur + Fc[o];
  }
}
__global__ __launch_bounds__(1024) void ssm_c_k(const float* __restrict__ hid, const float* __restrict__ invr,
    const float* __restrict__ nw, const float* __restrict__ av, const float* __restrict__ gn,
    const float* __restrict__ Init, float* __restrict__ hout){
  int c = blockIdx.x & 63, b = blockIdx.x >> 6;
  int d = threadIdx.x;
  float w   = nw[d];
  float g   = gn[d];
  float dec = 1.f/(1.f + expf(-av[d]));
  float od  = 1.f - dec;
  size_t rowoff = ((size_t)b*4096 + c*64)*1024 + d;
  const float* hp = hid + rowoff;
  float* op = hout + rowoff;
  const float* ip = invr + b*4096 + c*64;
  float hs = Init[((size_t)b*64 + c)*1024 + d];
  for (int i = 0; i < 64; ++i){
    float hv = hp[(size_t)i*1024];
    hs = dec*hs + od*(hv * ip[i] * w);
    op[(size_t)i*1024] = hv + hs*g;
  }
}

// ---------------- router scores ----------------
__global__ __launch_bounds__(256) void score_k(const float* __restrict__ h, const float* __restrict__ rw,
                                               float* __restrict__ sc){
  int row  = blockIdx.x * 4 + (threadIdx.x >> 6);
  int lane = threadIdx.x & 63;
  const float* p = h + (size_t)row * 1024;
  float s = 0.f;
  #pragma unroll
  for (int j = 0; j < 4; ++j){
    float4 v = *(const float4*)&p[lane*4 + j*256];
    float4 w = *(const float4*)&rw[lane*4 + j*256];
    s += v.x*w.x + v.y*w.y + v.z*w.z + v.w*w.w;
  }
  #pragma unroll
  for (int o = 1; o < 64; o <<= 1) s += __shfl_xor(s, o);
  if (lane == 0) sc[row] = s;
}

__global__ __launch_bounds__(256) void aux_k(const float* __restrict__ sc, float* __restrict__ out){
  __shared__ float red[256];
  int tid = threadIdx.x;
  float s = 0.f;
  for (int i = tid; i < 16384; i += 256) s += 1.f/(1.f + expf(-sc[i]));
  red[tid] = s; __syncthreads();
  for (int o = 128; o > 0; o >>= 1){ if (tid < o) red[tid] += red[tid+o]; __syncthreads(); }
  if (tid == 0) out[0] = red[0] * (1.f/16384.f);
}

// ---------------- top-k via bitonic sort (per batch) ----------------
__global__ __launch_bounds__(1024) void topk_k(const float* __restrict__ sc, int* __restrict__ idx,
                                               float* __restrict__ wsel){
  __shared__ float sv[4096];
  __shared__ int   si[4096];
  int b = blockIdx.x, tid = threadIdx.x;
  for (int i = tid; i < 4096; i += 1024){ sv[i] = sc[b*4096 + i]; si[i] = i; }
  __syncthreads();
  for (int k = 2; k <= 4096; k <<= 1)
    for (int j = k >> 1; j > 0; j >>= 1){
      for (int i = tid; i < 4096; i += 1024){
        int p = i ^ j;
        if (p > i){
          float vi = sv[i], vp = sv[p];
          int ii = si[i], ip = si[p];
          bool before = (vi > vp) || (vi == vp && ii < ip);
          bool desc = ((i & k) == 0);
          if (desc ? !before : before){ sv[i]=vp; sv[p]=vi; si[i]=ip; si[p]=ii; }
        }
      }
      __syncthreads();
    }
  for (int k = 2; k <= 1024; k <<= 1)
    for (int j = k >> 1; j > 0; j >>= 1){
      int i = tid, p = i ^ j;
      if (p > i){
        int a = si[i], c = si[p];
        bool asc = ((i & k) == 0);
        if (asc ? (a > c) : (a < c)){ si[i] = c; si[p] = a; }
      }
      __syncthreads();
    }
  int t = si[tid];
  idx[b*1024 + tid]  = t;
  wsel[b*1024 + tid] = 1.f/(1.f + expf(-sc[b*4096 + t]));
}

// ---------------- rmsnorm row -> bf16 (optional gather) ----------------
__global__ __launch_bounds__(256) void rownorm_bf16_k(const float* __restrict__ src, const float* __restrict__ w,
    u16* __restrict__ dst, const int* __restrict__ gidx, int base){
  int row  = blockIdx.x * 4 + (threadIdx.x >> 6);
  int lane = threadIdx.x & 63;
  size_t srow;
  if (gidx){ int b = row >> 10; srow = (size_t)b*4096 + gidx[row]; }
  else srow = (size_t)(base + row);
  const float* p = src + srow*1024;
  float4 v[4]; float ss = 0.f;
  #pragma unroll
  for (int j = 0; j < 4; ++j){
    v[j] = *(const float4*)&p[lane*4 + j*256];
    ss += v[j].x*v[j].x + v[j].y*v[j].y + v[j].z*v[j].z + v[j].w*v[j].w;
  }
  #pragma unroll
  for (int o = 1; o < 64; o <<= 1) ss += __shfl_xor(ss, o);
  float inv = 1.f / sqrtf(ss * (1.f/1024.f) + 1e-6f);
  #pragma unroll
  for (int j = 0; j < 4; ++j){
    float4 wv = *(const float4*)&w[lane*4 + j*256];
    ushort4 o4;
    o4.x = f2bf(v[j].x*inv*wv.x);
    o4.y = f2bf(v[j].y*inv*wv.y);
    o4.z = f2bf(v[j].z*inv*wv.z);
    o4.w = f2bf(v[j].w*inv*wv.w);
    *(ushort4*)&dst[(size_t)row*1024 + lane*4 + j*256] = o4;
  }
}

// ---------------- GEMM 256-tile, BK=64, 512 thr (WMxWN waves), dbuf LDS + 1-tile prefetch ----------
// A[M,K] bf16 x BT[N,K] bf16. Swizzled LDS via pre-swizzled global source (rule 21).
// EPI: 0 = store bf16, 1 = silu->bf16, 2 = += fp32, 3 = scatter-add (wo)
template<int BN, int WM, int WN, int EPI, int MINW>
__global__ __launch_bounds__(512, MINW) void gemm8(const u16* __restrict__ A, const u16* __restrict__ BT,
    u16* __restrict__ Cb, float* __restrict__ Cf, int M, int N, int K,
    const int* __restrict__ gidx, const float* __restrict__ wsel){
  constexpr int WROWS = 256 / WM;       // per-wave output rows
  constexpr int WCOLS = BN / WN;        // per-wave output cols
  constexpr int MI = WROWS / 16;
  constexpr int NI = WCOLS / 16;
  constexpr int BR = BN / 64;           // B staging rounds
  __shared__ u16 As[2][256*64];
  __shared__ u16 Bs[2][BN*64];

  int tid = threadIdx.x, wave = tid >> 6, lane = tid & 63;
  int lr = lane & 15, lg = lane >> 4;
  int wm = wave / WN, wn = wave % WN;

  // bijective XCD-aware block swizzle (m204): same-XCD blocks share bn (weight panel)
  int lin = blockIdx.x + gridDim.x * blockIdx.y;
  int nwg = gridDim.x * gridDim.y;
  int q = nwg >> 3, r = nwg & 7;
  int xc = lin & 7, of = lin >> 3;
  int s = (xc < r ? xc*(q+1) : r*(q+1) + (xc-r)*q) + of;
  int bm = s % gridDim.x, bn = s / gridDim.x;

  f32x4 zero4 = {0.f,0.f,0.f,0.f};
  f32x4 acc[MI][NI];
  #pragma unroll
  for (int mi = 0; mi < MI; ++mi)
    #pragma unroll
    for (int ni = 0; ni < NI; ++ni) acc[mi][ni] = zero4;

  // staging geometry: round rr covers LDS rows [rr*64, rr*64+64); wave w -> rows w*8..w*8+7
  int srow = (wave << 3) + (lane >> 3);         // 0..63 within round
  int glog = (lane & 7) ^ (srow & 7);           // pre-swizzled source group
  const size_t Kb = (size_t)K * 2;
  const char* aptr[4];
  const char* bptr[BR];
  #pragma unroll
  for (int rr = 0; rr < 4; ++rr)
    aptr[rr] = (const char*)A + (size_t)(bm*256 + rr*64 + srow) * Kb + glog*16;
  #pragma unroll
  for (int rr = 0; rr < BR; ++rr)
    bptr[rr] = (const char*)BT + (size_t)(bn*BN + rr*64 + srow) * Kb + glog*16;

  int nkt = K >> 6;
  // prologue: stage tile 0 into buf 0
  #pragma unroll
  for (int rr = 0; rr < 4; ++rr) gload16(aptr[rr], &As[0][(rr*64 + (wave<<3))*64]);
  #pragma unroll
  for (int rr = 0; rr < BR; ++rr) gload16(bptr[rr], &Bs[0][(rr*64 + (wave<<3))*64]);
  __syncthreads();

  for (int kt = 0; kt < nkt; ++kt){
    int bi = kt & 1;
    if (kt + 1 < nkt){
      size_t koff = (size_t)(kt + 1) << 7;   // *128 bytes
      #pragma unroll
      for (int rr = 0; rr < 4; ++rr) gload16(aptr[rr] + koff, &As[bi^1][(rr*64 + (wave<<3))*64]);
      #pragma unroll
      for (int rr = 0; rr < BR; ++rr) gload16(bptr[rr] + koff, &Bs[bi^1][(rr*64 + (wave<<3))*64]);
    }
    __builtin_amdgcn_sched_barrier(0);   // keep prefetch issue ahead of compute

    // B fragments resident in regs (read once per K-tile)
    bf16x8 bfrag[NI][2];
    #pragma unroll
    for (int ni = 0; ni < NI; ++ni)
      #pragma unroll
      for (int ks = 0; ks < 2; ++ks){
        int row = wn*WCOLS + ni*16 + lr;
        int gl = (ks*4 + lg) ^ (row & 7);
        bfrag[ni][ks] = *(const bf16x8*)&Bs[bi][row*64 + gl*8];
      }
    #pragma unroll
    for (int mh = 0; mh < 2; ++mh){
      bf16x8 afrag[MI/2][2];
      #pragma unroll
      for (int i = 0; i < MI/2; ++i)
        #pragma unroll
        for (int ks = 0; ks < 2; ++ks){
          int row = wm*WROWS + (mh*(MI/2) + i)*16 + lr;
          int gl = (ks*4 + lg) ^ (row & 7);
          afrag[i][ks] = *(const bf16x8*)&As[bi][row*64 + gl*8];
        }
      #pragma unroll
      for (int i = 0; i < MI/2; ++i)
        #pragma unroll
        for (int ni = 0; ni < NI; ++ni){
          f32x4 a = acc[mh*(MI/2)+i][ni];
          a = mfma16(afrag[i][0], bfrag[ni][0], a);
          a = mfma16(afrag[i][1], bfrag[ni][1], a);
          acc[mh*(MI/2)+i][ni] = a;
        }
    }
    __syncthreads();   // implicit vmcnt(0) waits on prefetch issued ~full-iter ago (cheap)
  }

  #pragma unroll
  for (int mi = 0; mi < MI; ++mi){
    int rb = bm*256 + wm*WROWS + mi*16 + lg*4;
    #pragma unroll
    for (int ni = 0; ni < NI; ++ni){
      int col = bn*BN + wn*WCOLS + ni*16 + lr;
      f32x4 v = acc[mi][ni];
      if constexpr (EPI == 0){
        #pragma unroll
        for (int t = 0; t < 4; ++t) Cb[(size_t)(rb+t)*N + col] = f2bf(v[t]);
      } else if constexpr (EPI == 1){
        #pragma unroll
        for (int t = 0; t < 4; ++t){ float x = v[t]; Cb[(size_t)(rb+t)*N + col] = f2bf(x / (1.f + expf(-x))); }
      } else if constexpr (EPI == 2){
        #pragma unroll
        for (int t = 0; t < 4; ++t) Cf[(size_t)(rb+t)*N + col] += v[t];
      } else {
        #pragma unroll
        for (int t = 0; t < 4; ++t){
          int rr = rb + t;
          int bb = rr >> 10;
          float* hr = Cf + ((size_t)bb*4096 + gidx[rr])*1024;
          hr[col] += v[t] * wsel[rr];
        }
      }
    }
  }
}

// ---------------- flash attention body for one q-tile ----------------
DEV void attn_body(const u16* __restrict__ qkv, u16* __restrict__ obuf,
                   u16* Ks, u16* Vt, u16* Pl, int b, int hh, int qt){
  int tid = threadIdx.x;
  int wave = tid >> 6, lane = tid & 63;
  int lr = lane & 15, lg = lane >> 4;

  const u16* qrow = qkv + (size_t)(b*1024 + qt*64 + wave*16 + lr)*3072 + hh*64;
  bf16x8 qf0 = *(const bf16x8*)(qrow + lg*8);
  bf16x8 qf1 = *(const bf16x8*)(qrow + 32 + lg*8);

  f32x4 zero4 = {0.f,0.f,0.f,0.f};
  f32x4 oacc[4];
  #pragma unroll
  for (int d = 0; d < 4; ++d) oacc[d] = zero4;
  float m[4], s[4];
  #pragma unroll
  for (int t = 0; t < 4; ++t){ m[t] = -INFINITY; s[t] = 0.f; }

  int key0 = tid >> 3,         ce0 = (tid & 7) * 8;
  int key1 = (tid + 256) >> 3, ce1 = ((tid + 256) & 7) * 8;
  u16x8 kreg0, kreg1, vreg0, vreg1;

  const u16* kvbase = qkv + (size_t)(b*1024)*3072 + 1024 + hh*64;
  {
    const u16* g0 = kvbase + (size_t)key0*3072 + ce0;
    const u16* g1 = kvbase + (size_t)key1*3072 + ce1;
    kreg0 = *(const u16x8*)g0;  vreg0 = *(const u16x8*)(g0 + 1024);
    kreg1 = *(const u16x8*)g1;  vreg1 = *(const u16x8*)(g1 + 1024);
  }

  for (int kt = 0; kt <= qt; ++kt){
    __syncthreads();
    *(u16x8*)&Ks[swz16(key0, ce0 >> 3)] = kreg0;
    *(u16x8*)&Ks[swz16(key1, ce1 >> 3)] = kreg1;
    #pragma unroll
    for (int j = 0; j < 8; ++j) Vt[swze(ce0 + j, key0)] = vreg0[j];
    #pragma unroll
    for (int j = 0; j < 8; ++j) Vt[swze(ce1 + j, key1)] = vreg1[j];
    __syncthreads();
    if (kt < qt){
      const u16* g0 = kvbase + (size_t)((kt+1)*64 + key0)*3072 + ce0;
      const u16* g1 = kvbase + (size_t)((kt+1)*64 + key1)*3072 + ce1;
      kreg0 = *(const u16x8*)g0;  vreg0 = *(const u16x8*)(g0 + 1024);
      kreg1 = *(const u16x8*)g1;  vreg1 = *(const u16x8*)(g1 + 1024);
    }

    float sv[4][4];
    #pragma unroll
    for (int kb = 0; kb < 4; ++kb){
      f32x4 sa = zero4;
      bf16x8 k0f = *(const bf16x8*)&Ks[swz16(kb*16 + lr, lg)];
      bf16x8 k1f = *(const bf16x8*)&Ks[swz16(kb*16 + lr, 4 + lg)];
      sa = mfma16(qf0, k0f, sa);
      sa = mfma16(qf1, k1f, sa);
      #pragma unroll
      for (int t = 0; t < 4; ++t) sv[kb][t] = sa[t]*0.125f;
    }
    if (kt == qt){
      #pragma unroll
      for (int kb = 0; kb < 4; ++kb){
        int keyg = kb*16 + lr;
        #pragma unroll
        for (int t = 0; t < 4; ++t){
          int qg = wave*16 + lg*4 + t;
          if (keyg > qg) sv[kb][t] = -1e30f;
        }
      }
    }
    float mn[4], scale[4];
    #pragma unroll
    for (int t = 0; t < 4; ++t){
      float tm = fmaxf(fmaxf(sv[0][t], sv[1][t]), fmaxf(sv[2][t], sv[3][t]));
      #pragma unroll
      for (int o = 1; o < 16; o <<= 1) tm = fmaxf(tm, __shfl_xor(tm, o));
      mn[t] = fmaxf(m[t], tm);
      scale[t] = expf(m[t] - mn[t]);
      m[t] = mn[t];
    }
    float ps[4] = {0.f,0.f,0.f,0.f};
    #pragma unroll
    for (int kb = 0; kb < 4; ++kb)
      #pragma unroll
      for (int t = 0; t < 4; ++t){
        float p = expf(sv[kb][t] - mn[t]);
        ps[t] += p;
        Pl[wave*1024 + swze(lg*4 + t, kb*16 + lr)] = f2bf(p);
      }
    #pragma unroll
    for (int t = 0; t < 4; ++t){
      #pragma unroll
      for (int o = 1; o < 16; o <<= 1) ps[t] += __shfl_xor(ps[t], o);
      s[t] = s[t]*scale[t] + ps[t];
    }
    #pragma unroll
    for (int d = 0; d < 4; ++d){
      f32x4 v = oacc[d];
      #pragma unroll
      for (int t = 0; t < 4; ++t) v[t] *= scale[t];
      oacc[d] = v;
    }
    bf16x8 pa0 = *(const bf16x8*)&Pl[wave*1024 + swz16(lr, lg)];
    bf16x8 pa1 = *(const bf16x8*)&Pl[wave*1024 + swz16(lr, 4 + lg)];
    #pragma unroll
    for (int d = 0; d < 4; ++d){
      bf16x8 v0 = *(const bf16x8*)&Vt[swz16(d*16 + lr, lg)];
      bf16x8 v1 = *(const bf16x8*)&Vt[swz16(d*16 + lr, 4 + lg)];
      oacc[d] = mfma16(pa0, v0, oacc[d]);
      oacc[d] = mfma16(pa1, v1, oacc[d]);
    }
  }
  #pragma unroll
  for (int d = 0; d < 4; ++d)
    #pragma unroll
    for (int t = 0; t < 4; ++t){
      int qrel = qt*64 + wave*16 + lg*4 + t;
      float val = oacc[d][t] / s[t];
      obuf[(size_t)(b*1024 + qrel)*1024 + hh*64 + d*16 + lr] = f2bf(val);
    }
}

// balanced: block handles q-tiles {qp, 15-qp} -> uniform 17 units of work
__global__ __launch_bounds__(256) void attn_k(const u16* __restrict__ qkv, u16* __restrict__ obuf){
  __shared__ u16 Ks[64*64];
  __shared__ u16 Vt[64*64];
  __shared__ u16 Pl[4*16*64];
  int blk = blockIdx.x;
  int qp = blk & 7;
  int hh = (blk >> 3) & 15;
  int b  = blk >> 7;
  attn_body(qkv, obuf, Ks, Vt, Pl, b, hh, qp);
  attn_body(qkv, obuf, Ks, Vt, Pl, b, hh, 15 - qp);
}

// ---------------- launch ----------------
extern "C" void kernel_launch(void* const* d_in, const int* in_sizes, int n_in,
                              void* d_out, int out_size, void* d_ws, size_t ws_size,
                              hipStream_t stream) {
  const float* hid    = (const float*)d_in[0];
  const float* nssm   = (const float*)d_in[1];
  const float* ssma   = (const float*)d_in[2];
  const float* ssmg   = (const float*)d_in[3];
  const float* routw  = (const float*)d_in[4];
  const float* nattn  = (const float*)d_in[5];
  const float* wq     = (const float*)d_in[6];
  const float* wk     = (const float*)d_in[7];
  const float* wv     = (const float*)d_in[8];
  const float* wo     = (const float*)d_in[9];
  const float* nffn   = (const float*)d_in[10];
  const float* w1     = (const float*)d_in[11];
  const float* w2     = (const float*)d_in[12];

  float* hbuf = (float*)d_out;                 // h lives in d_out [4,4096,1024]
  char* wsb = (char*)d_ws;
  u16*   wqkvT  = (u16*)(wsb + 0);             // [3072][1024] bf16
  u16*   woT    = (u16*)(wsb + 6291456);       // [1024][1024]
  u16*   w1T    = (u16*)(wsb + 8388608);       // [4096][1024]
  u16*   w2T    = (u16*)(wsb + 16777216);      // [1024][4096]
  float* invr   = (float*)(wsb + 25165824);    // [B*S]
  float* scores = (float*)(wsb + 25231360);    // [B*S]
  float* Fc     = (float*)(wsb + 25296896);    // [B,64,1024]
  float* Init   = (float*)(wsb + 26345472);    // [B,64,1024]
  int*   idxb   = (int*)(wsb + 27394048);      // [B,1024]
  float* wselb  = (float*)(wsb + 27410432);    // [B,1024]
  u16*   xn     = (u16*)(wsb + 27426816);      // [4096][1024] bf16
  u16*   qkv    = (u16*)(wsb + 35815424);      // [4096][3072] bf16
  u16*   obuf   = (u16*)(wsb + 60981248);      // [4096][1024] bf16
  // FFN phase (after WO gemm): reuse idxb-onward region
  u16*   xf     = (u16*)(wsb + 27394048);      // [4096][1024] bf16 (8 MB)
  u16*   act    = (u16*)(wsb + 35782656);      // [4096][4096] bf16 (32 MB)

  // weights -> bf16 transposed
  transpose_cast<<<dim3(32,32),  256, 0, stream>>>(wq, wqkvT,              1024, 1024);
  transpose_cast<<<dim3(32,32),  256, 0, stream>>>(wk, wqkvT + 1048576,    1024, 1024);
  transpose_cast<<<dim3(32,32),  256, 0, stream>>>(wv, wqkvT + 2097152,    1024, 1024);
  transpose_cast<<<dim3(32,32),  256, 0, stream>>>(wo, woT,                1024, 1024);
  transpose_cast<<<dim3(32,128), 256, 0, stream>>>(w1, w1T,                1024, 4096);
  transpose_cast<<<dim3(128,32), 256, 0, stream>>>(w2, w2T,                4096, 1024);

  // SSM
  rms_inv_k<<<4096, 256, 0, stream>>>(hid, invr);
  ssm_a_k<<<256, 1024, 0, stream>>>(hid, invr, nssm, ssma, Fc);
  ssm_b_k<<<4,   1024, 0, stream>>>(Fc, Init, ssma);
  ssm_c_k<<<256, 1024, 0, stream>>>(hid, invr, nssm, ssma, ssmg, Init, hbuf);

  // router
  score_k<<<4096, 256, 0, stream>>>(hbuf, routw, scores);
  aux_k<<<1, 256, 0, stream>>>(scores, hbuf + 16777216);
  topk_k<<<4, 1024, 0, stream>>>(scores, idxb, wselb);

  // attention path
  rownorm_bf16_k<<<1024, 256, 0, stream>>>(hbuf, nattn, xn, idxb, 0);
  gemm8<256,2,4,0,2><<<dim3(16,12), 512, 0, stream>>>(xn, wqkvT, qkv, nullptr, 4096, 3072, 1024, nullptr, nullptr);
  attn_k<<<512, 256, 0, stream>>>(qkv, obuf);
  gemm8<64,4,2,3,4><<<dim3(16,16), 512, 0, stream>>>(obuf, woT, nullptr, hbuf, 4096, 1024, 1024, idxb, wselb);

  // FFN in 4 row-chunks of 4096
  for (int ch = 0; ch < 4; ++ch){
    int m0 = ch * 4096;
    rownorm_bf16_k<<<1024, 256, 0, stream>>>(hbuf, nffn, xf, nullptr, m0);
    gemm8<256,2,4,1,2><<<dim3(16,16), 512, 0, stream>>>(xf, w1T, act, nullptr, 4096, 4096, 1024, nullptr, nullptr);
    gemm8<64,4,2,2,4><<<dim3(16,16), 512, 0, stream>>>(act, w2T, nullptr, hbuf + (size_t)m0*1024, 4096, 1024, 4096, nullptr, nullptr);
  }
  (void)in_sizes; (void)n_in; (void)out_size; (void)ws_size;
}